// Round 6
// baseline (194.612 us; speedup 1.0000x reference)
//
#include <hip/hip_runtime.h>
#include <cstddef>

#define NB   8
#define NPTS 4096
#define KNN  16
#define CAP  20    // per (q,chunk,half) phase-2 list capacity

typedef _Float16 h2 __attribute__((ext_vector_type(2)));
typedef _Float16 h8 __attribute__((ext_vector_type(8)));
typedef float    f4 __attribute__((ext_vector_type(4)));

static __device__ __forceinline__ h2 pk2(float a, float b) {
    return __builtin_bit_cast(h2, __builtin_amdgcn_cvt_pkrtz(a, b));
}

// Exact f32 distance (sq-form). Same fmaf nesting as prep's sq -> self-dist
// is exactly 0. Used ONLY in the final exact re-select.
static __device__ __forceinline__ float dist2(float4 Q, float4 p) {
    float dot = fmaf(Q.z, p.z, fmaf(Q.y, p.y, Q.x * p.x));
    return fmaf(-2.0f, dot, Q.w + p.w);
}

// ---------------------------------------------------------------------------
// Kernel P: pack pts4[b][n] = (x, y, z, x*x+y*y+z*z) from xyz[B][3][N]
// ---------------------------------------------------------------------------
__global__ __launch_bounds__(256) void prep_kernel(const float* __restrict__ xyz,
                                                   float4* __restrict__ pts4) {
    int i = blockIdx.x * 256 + threadIdx.x;
    int b = i >> 12;
    int n = i & (NPTS - 1);
    const float* base = xyz + (size_t)b * 3 * NPTS;
    float x = base[n];
    float y = base[NPTS + n];
    float z = base[2 * NPTS + n];
    float sq = fmaf(z, z, fmaf(y, y, x * x));   // same nesting as dist2's dot
    pts4[i] = make_float4(x, y, z, sq);
}

// ---------------------------------------------------------------------------
// Kernel A: exact 16-NN via packed-f16 pruning + exact f32 final select.
//  Block: 1024 thr = 16 waves; 64 queries x 8 chunks x 2 half-chunks.
//  q = (wave>>3)*32 + (lane&31), ch = wave&7, h = lane>>5.
//  Stage: P as h2 pairs {x2,y2,z2,pad} (16B / 2 points, RN-converted).
//  Phase 1: per lane, 2 subchunks x packed branchless sorted-4 chain
//           -> 16 f16 partial values (4 streams of 64 cands x top-4).
//  Merge (tid<64): tau_hat = 16th smallest of 256 partials (u16-bit order),
//           inflate by rigorous f16 error margin -> tau_cmp (f16 bits, +1ulp).
//  Phase 2: collect indices with d_h <= tau_cmp (u16 compare), cap CAP.
//  Final (tid<64): exact f32 distances from global pts4; pass A: 16th
//           smallest; pass B: emit d<dth in index order, then d==dth.
//           == jax.lax.top_k lowest-index tie-break (proven in rounds 2-5).
// ---------------------------------------------------------------------------
__global__ __launch_bounds__(1024, 8) void knn_kernel(const float4* __restrict__ pts4,
                                                      int* __restrict__ idxout) {
    __shared__ uint4 Ph[NPTS / 2];                    // 32 KB packed f16 coords
    __shared__ char  sbuf[64 * 8 * 2 * CAP * 2];      // 40 KB: partials / lists
    __shared__ unsigned int  tauv[64];
    __shared__ unsigned char cntb[64 * 16];

    unsigned int* partials = (unsigned int*)sbuf;     // [64][8][2][8] uint
    unsigned short* lists  = (unsigned short*)sbuf;   // [64][8][2][CAP] ushort

    int tid = threadIdx.x;
    int b   = blockIdx.y;
    const float4* pb = pts4 + (size_t)b * NPTS;

    // ---- stage packed-f16 points (RN conversion) ----
    for (int j = tid; j < NPTS / 2; j += 1024) {
        float4 p0 = pb[2 * j], p1 = pb[2 * j + 1];
        h2 hx = { (_Float16)p0.x, (_Float16)p1.x };
        h2 hy = { (_Float16)p0.y, (_Float16)p1.y };
        h2 hz = { (_Float16)p0.z, (_Float16)p1.z };
        Ph[j] = make_uint4(__builtin_bit_cast(unsigned int, hx),
                           __builtin_bit_cast(unsigned int, hy),
                           __builtin_bit_cast(unsigned int, hz), 0u);
    }

    int wave = tid >> 6, lane = tid & 63;
    int q  = (wave >> 3) * 32 + (lane & 31);   // 0..63
    int ch = wave & 7;                         // chunk
    int h  = lane >> 5;                        // half-chunk
    int nq = blockIdx.x * 64 + q;

    float4 qf = pb[nq];
    h2 qx2 = { (_Float16)qf.x, (_Float16)qf.x };
    h2 qy2 = { (_Float16)qf.y, (_Float16)qf.y };
    h2 qz2 = { (_Float16)qf.z, (_Float16)qf.z };
    __syncthreads();

    int jg0 = ch * 256 + h * 128;              // first point-pair group
    // ---- phase 1: 2 subchunks x packed branchless top-4 ----
    {
        int pbase = ((q * 8 + ch) * 2 + h) * 8;
        h2 binf = __builtin_bit_cast(h2, 0x7C007C00u);
#pragma unroll
        for (int sc = 0; sc < 2; ++sc) {
            h2 c0 = binf, c1 = binf, c2 = binf, c3 = binf;
            const uint4* src = &Ph[jg0 + sc * 64];
#pragma unroll 4
            for (int jj = 0; jj < 64; ++jj) {
                uint4 u = src[jj];
                h2 dx = __builtin_bit_cast(h2, u.x) - qx2;
                h2 dy = __builtin_bit_cast(h2, u.y) - qy2;
                h2 dz = __builtin_bit_cast(h2, u.z) - qz2;
                h2 d  = __builtin_elementwise_fma(dx, dx,
                         __builtin_elementwise_fma(dy, dy, dz * dz));
                h2 t;
                t = __builtin_elementwise_min(d, c0); d = __builtin_elementwise_max(d, c0); c0 = t;
                t = __builtin_elementwise_min(d, c1); d = __builtin_elementwise_max(d, c1); c1 = t;
                t = __builtin_elementwise_min(d, c2); d = __builtin_elementwise_max(d, c2); c2 = t;
                t = __builtin_elementwise_min(d, c3); d = __builtin_elementwise_max(d, c3); c3 = t;
            }
            int sw = q & 7;
            partials[pbase + ((sc * 4 + 0) ^ sw)] = __builtin_bit_cast(unsigned int, c0);
            partials[pbase + ((sc * 4 + 1) ^ sw)] = __builtin_bit_cast(unsigned int, c1);
            partials[pbase + ((sc * 4 + 2) ^ sw)] = __builtin_bit_cast(unsigned int, c2);
            partials[pbase + ((sc * 4 + 3) ^ sw)] = __builtin_bit_cast(unsigned int, c3);
        }
    }
    __syncthreads();

    // ---- merge: tau_hat (u16-bit order == f16 order for nonneg) ----
    if (tid < 64) {
        unsigned int mb[16];
#pragma unroll
        for (int j = 0; j < 16; ++j) mb[j] = 0x7FFFFFFFu;
        const unsigned int* pp = partials + tid * 128;
        int sw = tid & 7;
        for (int w = 0; w < 128; ++w) {
            unsigned int u = pp[(w & ~7) | ((w ^ sw) & 7)];
            unsigned int v = u & 0xFFFFu;
#pragma unroll
            for (int hf = 0; hf < 2; ++hf) {
                if (v < mb[15]) {
                    unsigned int x = v;
#pragma unroll
                    for (int j = 0; j < 16; ++j) {
                        unsigned int lo = x < mb[j] ? x : mb[j];
                        x = x > mb[j] ? x : mb[j];
                        mb[j] = lo;
                    }
                }
                v = u >> 16;
            }
        }
        // inflate: covers |d_h - d_f32| (coord RN err + f16 arith) both ways
        float tau = (float)__builtin_bit_cast(_Float16, (unsigned short)mb[15]);
        float tcf = tau + 0.04f * sqrtf(tau) + 2.5e-4f;
        unsigned int tcb = (unsigned int)__builtin_bit_cast(unsigned short, (_Float16)tcf) + 1u;
        tauv[tid] = tcb;
    }
    __syncthreads();   // partials dead; sbuf reused as lists

    // ---- phase 2: collect superset via u16 compare ----
    {
        unsigned int tcb = tauv[q];
        unsigned short* myl = lists + ((q * 8 + ch) * 2 + h) * CAP;
        int cA = 0;
        const uint4* src = &Ph[jg0];
#pragma unroll 2
        for (int jj = 0; jj < 128; ++jj) {
            uint4 u = src[jj];
            h2 dx = __builtin_bit_cast(h2, u.x) - qx2;
            h2 dy = __builtin_bit_cast(h2, u.y) - qy2;
            h2 dz = __builtin_bit_cast(h2, u.z) - qz2;
            h2 d  = __builtin_elementwise_fma(dx, dx,
                     __builtin_elementwise_fma(dy, dy, dz * dz));
            unsigned int du = __builtin_bit_cast(unsigned int, d);
            unsigned int lo = du & 0xFFFFu, hi = du >> 16;
            if (lo <= tcb) { if (cA < CAP) myl[cA] = (unsigned short)(2 * (jg0 + jj));     ++cA; }
            if (hi <= tcb) { if (cA < CAP) myl[cA] = (unsigned short)(2 * (jg0 + jj) + 1); ++cA; }
        }
        cntb[(q * 8 + ch) * 2 + h] = (unsigned char)(cA > CAP ? CAP : cA);
    }
    __syncthreads();

    // ---- final: exact f32 top-16 with top_k tie-break ----
    if (tid < 64) {
        int nqf = blockIdx.x * 64 + tid;
        float4 Qf = pb[nqf];
        float bd[16];
#pragma unroll
        for (int j = 0; j < 16; ++j) bd[j] = __builtin_inff();
        // pass A: 16th smallest exact distance
        for (int cc = 0; cc < 16; ++cc) {
            int nc = (int)cntb[tid * 16 + cc];
            const unsigned short* L = lists + (tid * 16 + cc) * CAP;
            for (int j = 0; j < nc; ++j) {
                float x = dist2(Qf, pb[L[j]]);
                if (x < bd[15]) {
#pragma unroll
                    for (int t = 0; t < 16; ++t) {
                        float lo = fminf(x, bd[t]);
                        x        = fmaxf(x, bd[t]);
                        bd[t]    = lo;
                    }
                }
            }
        }
        float dth = bd[15];
        int* op = idxout + ((size_t)b * NPTS + nqf) * KNN;
        int pos = 0;
        // pass B1: d < dth in ascending index order
        for (int cc = 0; cc < 16; ++cc) {
            int nc = (int)cntb[tid * 16 + cc];
            const unsigned short* L = lists + (tid * 16 + cc) * CAP;
            for (int j = 0; j < nc; ++j) {
                int idx = (int)L[j];
                if (dist2(Qf, pb[idx]) < dth && pos < 16) op[pos++] = idx;
            }
        }
        // pass B2: ties d == dth in ascending index order
        for (int cc = 0; cc < 16 && pos < 16; ++cc) {
            int nc = (int)cntb[tid * 16 + cc];
            const unsigned short* L = lists + (tid * 16 + cc) * CAP;
            for (int j = 0; j < nc; ++j) {
                int idx = (int)L[j];
                if (dist2(Qf, pb[idx]) == dth && pos < 16) op[pos++] = idx;
            }
        }
    }
}

// ---------------------------------------------------------------------------
// Kernel B: fully-register MFMA MLP (unchanged from round 4/5).
// ---------------------------------------------------------------------------
__global__ __launch_bounds__(256, 2) void mlp_kernel(
    const float4* __restrict__ pts4, const int* __restrict__ idxin,
    const float* __restrict__ W0, const float* __restrict__ b0,
    const float* __restrict__ W1, const float* __restrict__ b1,
    const float* __restrict__ W2, const float* __restrict__ b2,
    float* __restrict__ out) {

    int tid  = threadIdx.x;
    int wave = tid >> 6, lane = tid & 63;
    int g = lane >> 4, i = lane & 15;

    h2 w0x[8], w0y[8], w0z[8], w0b[8];
#pragma unroll
    for (int s = 0; s < 2; ++s)
#pragma unroll
        for (int v = 0; v < 4; ++v) {
            int c0 = 32 * s + 8 * g + 2 * v;
            w0x[s * 4 + v] = pk2(W0[c0 * 3 + 0], W0[c0 * 3 + 3]);
            w0y[s * 4 + v] = pk2(W0[c0 * 3 + 1], W0[c0 * 3 + 4]);
            w0z[s * 4 + v] = pk2(W0[c0 * 3 + 2], W0[c0 * 3 + 5]);
            w0b[s * 4 + v] = pk2(b0[c0], b0[c0 + 1]);
        }
    h2 b1p[8];
#pragma unroll
    for (int s = 0; s < 2; ++s)
#pragma unroll
        for (int v = 0; v < 4; ++v) {
            int c0 = 32 * s + 16 * (v >> 1) + 4 * g + 2 * (v & 1);
            b1p[s * 4 + v] = pk2(b1[c0], b1[c0 + 1]);
        }
    h8 wf1[4][2];
#pragma unroll
    for (int t = 0; t < 4; ++t)
#pragma unroll
        for (int s = 0; s < 2; ++s) {
            const float* p = W1 + (16 * t + i) * 64 + 32 * s + 8 * g;
            h8 f;
#pragma unroll
            for (int j = 0; j < 8; ++j) f[j] = (_Float16)p[j];
            wf1[t][s] = f;
        }
    h8 wf2[8][2];
#pragma unroll
    for (int t = 0; t < 8; ++t)
#pragma unroll
        for (int s = 0; s < 2; ++s) {
            const float* p = W2 + (16 * t + i) * 64;
            h8 f;
#pragma unroll
            for (int j = 0; j < 8; ++j) {
                int vc = 32 * s + 16 * (j >> 2) + 4 * g + (j & 3);
                f[j] = (_Float16)p[vc];
            }
            wf2[t][s] = f;
        }

    int gw = blockIdx.x * 4 + wave;
    int b  = gw >> 8;
    int n0 = (gw & 255) * 16;

    const float4* pb = pts4 + (size_t)b * NPTS;
    float4 q = pb[n0 + i];
    const int* ip = idxin + ((size_t)b * NPTS + n0 + i) * KNN;

    float mx[8][4];
#pragma unroll
    for (int t = 0; t < 8; ++t)
#pragma unroll
        for (int r = 0; r < 4; ++r) mx[t][r] = -3.4e38f;

    for (int it = 0; it < KNN; ++it) {
        int mi = ip[it];
        float4 p = pb[mi];
        float rx = p.x - q.x, ry = p.y - q.y, rz = p.z - q.z;
        h2 rxx = pk2(rx, rx), ryy = pk2(ry, ry), rzz = pk2(rz, rz);

        h8 h0f[2];
#pragma unroll
        for (int s = 0; s < 2; ++s)
#pragma unroll
            for (int v = 0; v < 4; ++v) {
                h2 hh = __builtin_elementwise_fma(w0z[s * 4 + v], rzz,
                         __builtin_elementwise_fma(w0y[s * 4 + v], ryy,
                          __builtin_elementwise_fma(w0x[s * 4 + v], rxx, w0b[s * 4 + v])));
                hh = __builtin_elementwise_max(hh, (h2)(_Float16)0.0f);
                h0f[s][2 * v]     = hh.x;
                h0f[s][2 * v + 1] = hh.y;
            }

        f4 d1[4];
#pragma unroll
        for (int t = 0; t < 4; ++t) {
            d1[t] = (f4)0.0f;
#pragma unroll
            for (int s = 0; s < 2; ++s)
                d1[t] = __builtin_amdgcn_mfma_f32_16x16x32_f16(wf1[t][s], h0f[s], d1[t], 0, 0, 0);
        }

        h8 h1f[2];
#pragma unroll
        for (int s = 0; s < 2; ++s)
#pragma unroll
            for (int v = 0; v < 4; ++v) {
                int t = 2 * s + (v >> 1), r0 = 2 * (v & 1);
                h2 w = pk2(d1[t][r0], d1[t][r0 + 1]);
                w = w + b1p[s * 4 + v];
                w = __builtin_elementwise_max(w, (h2)(_Float16)0.0f);
                h1f[s][2 * v]     = w.x;
                h1f[s][2 * v + 1] = w.y;
            }

#pragma unroll
        for (int t = 0; t < 8; ++t) {
            f4 d2 = (f4)0.0f;
#pragma unroll
            for (int s = 0; s < 2; ++s)
                d2 = __builtin_amdgcn_mfma_f32_16x16x32_f16(wf2[t][s], h1f[s], d2, 0, 0, 0);
#pragma unroll
            for (int r = 0; r < 4; ++r) mx[t][r] = fmaxf(mx[t][r], d2[r]);
        }
    }

    size_t ob = (size_t)b * 128 * NPTS + n0 + i;
#pragma unroll
    for (int t = 0; t < 8; ++t)
#pragma unroll
        for (int r = 0; r < 4; ++r) {
            int chn = 16 * t + 4 * g + r;
            float v = fmaxf(mx[t][r] + b2[chn], 0.0f);
            out[ob + (size_t)chn * NPTS] = v;
        }
}

// ---------------------------------------------------------------------------
extern "C" void kernel_launch(void* const* d_in, const int* in_sizes, int n_in,
                              void* d_out, int out_size, void* d_ws, size_t ws_size,
                              hipStream_t stream) {
    (void)in_sizes; (void)n_in; (void)out_size; (void)ws_size;
    const float* xyz = (const float*)d_in[0];
    const float* W0  = (const float*)d_in[1];
    const float* b0  = (const float*)d_in[2];
    const float* W1  = (const float*)d_in[3];
    const float* b1  = (const float*)d_in[4];
    const float* W2  = (const float*)d_in[5];
    const float* b2  = (const float*)d_in[6];
    float* out = (float*)d_out;

    char* ws = (char*)d_ws;
    float4* pts4 = (float4*)ws;                                     // 512 KB
    int*    idxb = (int*)(ws + (size_t)NB * NPTS * sizeof(float4)); // 2 MB

    prep_kernel<<<dim3(NB * NPTS / 256), dim3(256), 0, stream>>>(xyz, pts4);
    knn_kernel<<<dim3(NPTS / 64, NB), dim3(1024), 0, stream>>>(pts4, idxb);
    mlp_kernel<<<dim3(512), dim3(256), 0, stream>>>(
        pts4, idxb, W0, b0, W1, b1, W2, b2, out);
}

// Round 7
// 186.762 us; speedup vs baseline: 1.0420x; 1.0420x over previous
//
#include <hip/hip_runtime.h>
#include <cstddef>

#define NB   8
#define NPTS 4096
#define KNN  16
#define CAP  16    // per (q,chunk,half) phase-2 list capacity

typedef _Float16 h2 __attribute__((ext_vector_type(2)));
typedef _Float16 h8 __attribute__((ext_vector_type(8)));
typedef float    f4 __attribute__((ext_vector_type(4)));

static __device__ __forceinline__ h2 pk2(float a, float b) {
    return __builtin_bit_cast(h2, __builtin_amdgcn_cvt_pkrtz(a, b));
}

// Exact f32 distance (sq-form). Same fmaf nesting as prep's sq -> self-dist
// is exactly 0. Used ONLY in the final exact re-select.
static __device__ __forceinline__ float dist2(float4 Q, float4 p) {
    float dot = fmaf(Q.z, p.z, fmaf(Q.y, p.y, Q.x * p.x));
    return fmaf(-2.0f, dot, Q.w + p.w);
}

// ---------------------------------------------------------------------------
// Kernel P: pack pts4[b][n] = (x, y, z, x*x+y*y+z*z) from xyz[B][3][N]
// ---------------------------------------------------------------------------
__global__ __launch_bounds__(256) void prep_kernel(const float* __restrict__ xyz,
                                                   float4* __restrict__ pts4) {
    int i = blockIdx.x * 256 + threadIdx.x;
    int b = i >> 12;
    int n = i & (NPTS - 1);
    const float* base = xyz + (size_t)b * 3 * NPTS;
    float x = base[n];
    float y = base[NPTS + n];
    float z = base[2 * NPTS + n];
    float sq = fmaf(z, z, fmaf(y, y, x * x));   // same nesting as dist2's dot
    pts4[i] = make_float4(x, y, z, sq);
}

// ---------------------------------------------------------------------------
// Kernel A: exact 16-NN via packed-f16 pruning + exact f32 final select.
//  vs round 6: SoA f16 coord staging (3x b128 per 8 cands, -25% LDS traffic),
//  LDS total 57.3KB (-> 2 blocks/CU), transposed partials [slot][q]
//  (conflict-free phase-1 writes AND merge reads).
// ---------------------------------------------------------------------------
__global__ __launch_bounds__(1024, 8) void knn_kernel(const float4* __restrict__ pts4,
                                                      int* __restrict__ idxout) {
    __shared__ unsigned int Phx[NPTS / 2];            // 8 KB  x-pairs (h2)
    __shared__ unsigned int Phy[NPTS / 2];            // 8 KB
    __shared__ unsigned int Phz[NPTS / 2];            // 8 KB
    __shared__ char  sbuf[32768];                     // 32 KB partials / lists
    __shared__ unsigned int  tauv[64];
    __shared__ unsigned char cntb[64 * 16];

    unsigned int*   partials = (unsigned int*)sbuf;   // [128 slots][64 q]
    unsigned short* lists    = (unsigned short*)sbuf; // [64*16][CAP]

    int tid = threadIdx.x;
    int b   = blockIdx.y;
    const float4* pb = pts4 + (size_t)b * NPTS;

    // ---- stage SoA packed-f16 coords (RN conversion) ----
    for (int j = tid; j < NPTS / 2; j += 1024) {
        float4 p0 = pb[2 * j], p1 = pb[2 * j + 1];
        h2 hx = { (_Float16)p0.x, (_Float16)p1.x };
        h2 hy = { (_Float16)p0.y, (_Float16)p1.y };
        h2 hz = { (_Float16)p0.z, (_Float16)p1.z };
        Phx[j] = __builtin_bit_cast(unsigned int, hx);
        Phy[j] = __builtin_bit_cast(unsigned int, hy);
        Phz[j] = __builtin_bit_cast(unsigned int, hz);
    }

    int wave = tid >> 6, lane = tid & 63;
    int q  = (wave >> 3) * 32 + (lane & 31);   // 0..63
    int ch = wave & 7;                         // chunk
    int h  = lane >> 5;                        // half-chunk
    int nq = blockIdx.x * 64 + q;

    float4 qf = pb[nq];
    h2 qx2 = { (_Float16)qf.x, (_Float16)qf.x };
    h2 qy2 = { (_Float16)qf.y, (_Float16)qf.y };
    h2 qz2 = { (_Float16)qf.z, (_Float16)qf.z };
    __syncthreads();

    const uint4* X4 = (const uint4*)Phx;
    const uint4* Y4 = (const uint4*)Phy;
    const uint4* Z4 = (const uint4*)Phz;
    int jb4 = ch * 64 + h * 32;                // uint4 base (8 cands per uint4)

    // ---- phase 1: 2 groups of 128 cands, packed branchless top-4 each ----
    {
        int slotbase = (ch * 2 + h) * 8;
        h2 binf = __builtin_bit_cast(h2, 0x7C007C00u);
#pragma unroll
        for (int sc = 0; sc < 2; ++sc) {
            h2 c0 = binf, c1 = binf, c2 = binf, c3 = binf;
            auto chain = [&](unsigned ux, unsigned uy, unsigned uz) {
                h2 dx = __builtin_bit_cast(h2, ux) - qx2;
                h2 dy = __builtin_bit_cast(h2, uy) - qy2;
                h2 dz = __builtin_bit_cast(h2, uz) - qz2;
                h2 d  = __builtin_elementwise_fma(dx, dx,
                         __builtin_elementwise_fma(dy, dy, dz * dz));
                h2 t;
                t = __builtin_elementwise_min(d, c0); d = __builtin_elementwise_max(d, c0); c0 = t;
                t = __builtin_elementwise_min(d, c1); d = __builtin_elementwise_max(d, c1); c1 = t;
                t = __builtin_elementwise_min(d, c2); d = __builtin_elementwise_max(d, c2); c2 = t;
                t = __builtin_elementwise_min(d, c3); d = __builtin_elementwise_max(d, c3); c3 = t;
            };
#pragma unroll 4
            for (int j4 = 0; j4 < 16; ++j4) {
                uint4 xu = X4[jb4 + sc * 16 + j4];
                uint4 yu = Y4[jb4 + sc * 16 + j4];
                uint4 zu = Z4[jb4 + sc * 16 + j4];
                chain(xu.x, yu.x, zu.x);
                chain(xu.y, yu.y, zu.y);
                chain(xu.z, yu.z, zu.z);
                chain(xu.w, yu.w, zu.w);
            }
            // transposed: [slot][q] -> writes hit bank q%32 (2-way, free)
            partials[(slotbase + sc * 4 + 0) * 64 + q] = __builtin_bit_cast(unsigned int, c0);
            partials[(slotbase + sc * 4 + 1) * 64 + q] = __builtin_bit_cast(unsigned int, c1);
            partials[(slotbase + sc * 4 + 2) * 64 + q] = __builtin_bit_cast(unsigned int, c2);
            partials[(slotbase + sc * 4 + 3) * 64 + q] = __builtin_bit_cast(unsigned int, c3);
        }
    }
    __syncthreads();

    // ---- merge (one wave): tau_hat = 16th smallest of 256 f16 partials ----
    if (tid < 64) {
        unsigned int mb[16];
#pragma unroll
        for (int j = 0; j < 16; ++j) mb[j] = 0x7FFFFFFFu;
        for (int slot = 0; slot < 128; ++slot) {
            unsigned int u = partials[slot * 64 + tid];   // lane-consecutive
            unsigned int v = u & 0xFFFFu;
#pragma unroll
            for (int hf = 0; hf < 2; ++hf) {
                if (v < mb[15]) {
                    unsigned int x = v;
#pragma unroll
                    for (int j = 0; j < 16; ++j) {
                        unsigned int lo = x < mb[j] ? x : mb[j];
                        x = x > mb[j] ? x : mb[j];
                        mb[j] = lo;
                    }
                }
                v = u >> 16;
            }
        }
        // inflate: covers |d_h - d_f32| (coord RN err + f16 arith) both ways
        float tau = (float)__builtin_bit_cast(_Float16, (unsigned short)mb[15]);
        float tcf = tau + 0.04f * sqrtf(tau) + 2.5e-4f;
        unsigned int tcb = (unsigned int)__builtin_bit_cast(unsigned short, (_Float16)tcf) + 1u;
        tauv[tid] = tcb;
    }
    __syncthreads();   // partials dead; sbuf reused as lists

    // ---- phase 2: collect superset via u16 compare ----
    {
        unsigned int tcb = tauv[q];
        unsigned short* myl = lists + (q * 16 + ch * 2 + h) * CAP;
        int cA = 0;
        auto coll = [&](unsigned ux, unsigned uy, unsigned uz, int ce) {
            h2 dx = __builtin_bit_cast(h2, ux) - qx2;
            h2 dy = __builtin_bit_cast(h2, uy) - qy2;
            h2 dz = __builtin_bit_cast(h2, uz) - qz2;
            h2 d  = __builtin_elementwise_fma(dx, dx,
                     __builtin_elementwise_fma(dy, dy, dz * dz));
            unsigned int du = __builtin_bit_cast(unsigned int, d);
            if ((du & 0xFFFFu) <= tcb) { if (cA < CAP) myl[cA] = (unsigned short)ce;       ++cA; }
            if ((du >> 16)     <= tcb) { if (cA < CAP) myl[cA] = (unsigned short)(ce + 1); ++cA; }
        };
#pragma unroll 2
        for (int j4 = 0; j4 < 32; ++j4) {
            uint4 xu = X4[jb4 + j4];
            uint4 yu = Y4[jb4 + j4];
            uint4 zu = Z4[jb4 + j4];
            int cb = ((jb4 + j4) * 4) * 2;
            coll(xu.x, yu.x, zu.x, cb);
            coll(xu.y, yu.y, zu.y, cb + 2);
            coll(xu.z, yu.z, zu.z, cb + 4);
            coll(xu.w, yu.w, zu.w, cb + 6);
        }
        cntb[q * 16 + ch * 2 + h] = (unsigned char)(cA > CAP ? CAP : cA);
    }
    __syncthreads();

    // ---- final: exact f32 top-16 with top_k tie-break ----
    if (tid < 64) {
        int nqf = blockIdx.x * 64 + tid;
        float4 Qf = pb[nqf];
        float bd[16];
#pragma unroll
        for (int j = 0; j < 16; ++j) bd[j] = __builtin_inff();
        // pass A: 16th smallest exact distance
        for (int cc = 0; cc < 16; ++cc) {
            int nc = (int)cntb[tid * 16 + cc];
            const unsigned short* L = lists + (tid * 16 + cc) * CAP;
            for (int j = 0; j < nc; ++j) {
                float x = dist2(Qf, pb[L[j]]);
                if (x < bd[15]) {
#pragma unroll
                    for (int t = 0; t < 16; ++t) {
                        float lo = fminf(x, bd[t]);
                        x        = fmaxf(x, bd[t]);
                        bd[t]    = lo;
                    }
                }
            }
        }
        float dth = bd[15];
        int* op = idxout + ((size_t)b * NPTS + nqf) * KNN;
        int pos = 0;
        // pass B1: d < dth in ascending index order
        for (int cc = 0; cc < 16; ++cc) {
            int nc = (int)cntb[tid * 16 + cc];
            const unsigned short* L = lists + (tid * 16 + cc) * CAP;
            for (int j = 0; j < nc; ++j) {
                int idx = (int)L[j];
                if (dist2(Qf, pb[idx]) < dth && pos < 16) op[pos++] = idx;
            }
        }
        // pass B2: ties d == dth in ascending index order
        for (int cc = 0; cc < 16 && pos < 16; ++cc) {
            int nc = (int)cntb[tid * 16 + cc];
            const unsigned short* L = lists + (tid * 16 + cc) * CAP;
            for (int j = 0; j < nc; ++j) {
                int idx = (int)L[j];
                if (dist2(Qf, pb[idx]) == dth && pos < 16) op[pos++] = idx;
            }
        }
    }
}

// ---------------------------------------------------------------------------
// Kernel B: fully-register MFMA MLP (unchanged from round 4/5/6).
// ---------------------------------------------------------------------------
__global__ __launch_bounds__(256, 2) void mlp_kernel(
    const float4* __restrict__ pts4, const int* __restrict__ idxin,
    const float* __restrict__ W0, const float* __restrict__ b0,
    const float* __restrict__ W1, const float* __restrict__ b1,
    const float* __restrict__ W2, const float* __restrict__ b2,
    float* __restrict__ out) {

    int tid  = threadIdx.x;
    int wave = tid >> 6, lane = tid & 63;
    int g = lane >> 4, i = lane & 15;

    h2 w0x[8], w0y[8], w0z[8], w0b[8];
#pragma unroll
    for (int s = 0; s < 2; ++s)
#pragma unroll
        for (int v = 0; v < 4; ++v) {
            int c0 = 32 * s + 8 * g + 2 * v;
            w0x[s * 4 + v] = pk2(W0[c0 * 3 + 0], W0[c0 * 3 + 3]);
            w0y[s * 4 + v] = pk2(W0[c0 * 3 + 1], W0[c0 * 3 + 4]);
            w0z[s * 4 + v] = pk2(W0[c0 * 3 + 2], W0[c0 * 3 + 5]);
            w0b[s * 4 + v] = pk2(b0[c0], b0[c0 + 1]);
        }
    h2 b1p[8];
#pragma unroll
    for (int s = 0; s < 2; ++s)
#pragma unroll
        for (int v = 0; v < 4; ++v) {
            int c0 = 32 * s + 16 * (v >> 1) + 4 * g + 2 * (v & 1);
            b1p[s * 4 + v] = pk2(b1[c0], b1[c0 + 1]);
        }
    h8 wf1[4][2];
#pragma unroll
    for (int t = 0; t < 4; ++t)
#pragma unroll
        for (int s = 0; s < 2; ++s) {
            const float* p = W1 + (16 * t + i) * 64 + 32 * s + 8 * g;
            h8 f;
#pragma unroll
            for (int j = 0; j < 8; ++j) f[j] = (_Float16)p[j];
            wf1[t][s] = f;
        }
    h8 wf2[8][2];
#pragma unroll
    for (int t = 0; t < 8; ++t)
#pragma unroll
        for (int s = 0; s < 2; ++s) {
            const float* p = W2 + (16 * t + i) * 64;
            h8 f;
#pragma unroll
            for (int j = 0; j < 8; ++j) {
                int vc = 32 * s + 16 * (j >> 2) + 4 * g + (j & 3);
                f[j] = (_Float16)p[vc];
            }
            wf2[t][s] = f;
        }

    int gw = blockIdx.x * 4 + wave;
    int b  = gw >> 8;
    int n0 = (gw & 255) * 16;

    const float4* pb = pts4 + (size_t)b * NPTS;
    float4 q = pb[n0 + i];
    const int* ip = idxin + ((size_t)b * NPTS + n0 + i) * KNN;

    float mx[8][4];
#pragma unroll
    for (int t = 0; t < 8; ++t)
#pragma unroll
        for (int r = 0; r < 4; ++r) mx[t][r] = -3.4e38f;

    for (int it = 0; it < KNN; ++it) {
        int mi = ip[it];
        float4 p = pb[mi];
        float rx = p.x - q.x, ry = p.y - q.y, rz = p.z - q.z;
        h2 rxx = pk2(rx, rx), ryy = pk2(ry, ry), rzz = pk2(rz, rz);

        h8 h0f[2];
#pragma unroll
        for (int s = 0; s < 2; ++s)
#pragma unroll
            for (int v = 0; v < 4; ++v) {
                h2 hh = __builtin_elementwise_fma(w0z[s * 4 + v], rzz,
                         __builtin_elementwise_fma(w0y[s * 4 + v], ryy,
                          __builtin_elementwise_fma(w0x[s * 4 + v], rxx, w0b[s * 4 + v])));
                hh = __builtin_elementwise_max(hh, (h2)(_Float16)0.0f);
                h0f[s][2 * v]     = hh.x;
                h0f[s][2 * v + 1] = hh.y;
            }

        f4 d1[4];
#pragma unroll
        for (int t = 0; t < 4; ++t) {
            d1[t] = (f4)0.0f;
#pragma unroll
            for (int s = 0; s < 2; ++s)
                d1[t] = __builtin_amdgcn_mfma_f32_16x16x32_f16(wf1[t][s], h0f[s], d1[t], 0, 0, 0);
        }

        h8 h1f[2];
#pragma unroll
        for (int s = 0; s < 2; ++s)
#pragma unroll
            for (int v = 0; v < 4; ++v) {
                int t = 2 * s + (v >> 1), r0 = 2 * (v & 1);
                h2 w = pk2(d1[t][r0], d1[t][r0 + 1]);
                w = w + b1p[s * 4 + v];
                w = __builtin_elementwise_max(w, (h2)(_Float16)0.0f);
                h1f[s][2 * v]     = w.x;
                h1f[s][2 * v + 1] = w.y;
            }

#pragma unroll
        for (int t = 0; t < 8; ++t) {
            f4 d2 = (f4)0.0f;
#pragma unroll
            for (int s = 0; s < 2; ++s)
                d2 = __builtin_amdgcn_mfma_f32_16x16x32_f16(wf2[t][s], h1f[s], d2, 0, 0, 0);
#pragma unroll
            for (int r = 0; r < 4; ++r) mx[t][r] = fmaxf(mx[t][r], d2[r]);
        }
    }

    size_t ob = (size_t)b * 128 * NPTS + n0 + i;
#pragma unroll
    for (int t = 0; t < 8; ++t)
#pragma unroll
        for (int r = 0; r < 4; ++r) {
            int chn = 16 * t + 4 * g + r;
            float v = fmaxf(mx[t][r] + b2[chn], 0.0f);
            out[ob + (size_t)chn * NPTS] = v;
        }
}

// ---------------------------------------------------------------------------
extern "C" void kernel_launch(void* const* d_in, const int* in_sizes, int n_in,
                              void* d_out, int out_size, void* d_ws, size_t ws_size,
                              hipStream_t stream) {
    (void)in_sizes; (void)n_in; (void)out_size; (void)ws_size;
    const float* xyz = (const float*)d_in[0];
    const float* W0  = (const float*)d_in[1];
    const float* b0  = (const float*)d_in[2];
    const float* W1  = (const float*)d_in[3];
    const float* b1  = (const float*)d_in[4];
    const float* W2  = (const float*)d_in[5];
    const float* b2  = (const float*)d_in[6];
    float* out = (float*)d_out;

    char* ws = (char*)d_ws;
    float4* pts4 = (float4*)ws;                                     // 512 KB
    int*    idxb = (int*)(ws + (size_t)NB * NPTS * sizeof(float4)); // 2 MB

    prep_kernel<<<dim3(NB * NPTS / 256), dim3(256), 0, stream>>>(xyz, pts4);
    knn_kernel<<<dim3(NPTS / 64, NB), dim3(1024), 0, stream>>>(pts4, idxb);
    mlp_kernel<<<dim3(512), dim3(256), 0, stream>>>(
        pts4, idxb, W0, b0, W1, b1, W2, b2, out);
}

// Round 8
// 162.071 us; speedup vs baseline: 1.2008x; 1.1523x over previous
//
#include <hip/hip_runtime.h>
#include <cstddef>

#define NB   8
#define NPTS 4096
#define KNN  16
#define FCAP 56    // per-query compacted candidate list capacity

typedef _Float16 h2 __attribute__((ext_vector_type(2)));
typedef _Float16 h8 __attribute__((ext_vector_type(8)));
typedef float    f4 __attribute__((ext_vector_type(4)));

static __device__ __forceinline__ h2 pk2(float a, float b) {
    return __builtin_bit_cast(h2, __builtin_amdgcn_cvt_pkrtz(a, b));
}

// Exact f32 distance (sq-form). Same fmaf nesting as prep's sq -> self-dist
// is exactly 0. Used ONLY for the exact candidate distances.
static __device__ __forceinline__ float dist2(float4 Q, float4 p) {
    float dot = fmaf(Q.z, p.z, fmaf(Q.y, p.y, Q.x * p.x));
    return fmaf(-2.0f, dot, Q.w + p.w);
}

// ---------------------------------------------------------------------------
// Kernel P: pack pts4[b][n] = (x, y, z, x*x+y*y+z*z) from xyz[B][3][N]
// ---------------------------------------------------------------------------
__global__ __launch_bounds__(256) void prep_kernel(const float* __restrict__ xyz,
                                                   float4* __restrict__ pts4) {
    int i = blockIdx.x * 256 + threadIdx.x;
    int b = i >> 12;
    int n = i & (NPTS - 1);
    const float* base = xyz + (size_t)b * 3 * NPTS;
    float x = base[n];
    float y = base[NPTS + n];
    float z = base[2 * NPTS + n];
    float sq = fmaf(z, z, fmaf(y, y, x * x));   // same nesting as dist2's dot
    pts4[i] = make_float4(x, y, z, sq);
}

// ---------------------------------------------------------------------------
// Kernel A: exact 16-NN via packed-f16 pruning + exact f32 final select.
//  vs round 7: phase 2 materializes EXACT f32 distances in parallel (1024
//  threads, ~1.3 global gathers each) into one compacted per-query LDS list
//  (atomic append); final select is a single LDS-only lexicographic (d,idx)
//  top-16 insert chain == jax.lax.top_k stable tie-break. Removes the ~100us
//  serial 3-pass global-gather that dominated rounds 6/7.
// ---------------------------------------------------------------------------
__global__ __launch_bounds__(1024, 8) void knn_kernel(const float4* __restrict__ pts4,
                                                      int* __restrict__ idxout) {
    __shared__ unsigned int Phx[NPTS / 2];            // 8 KB  x-pairs (h2)
    __shared__ unsigned int Phy[NPTS / 2];            // 8 KB
    __shared__ unsigned int Phz[NPTS / 2];            // 8 KB
    __shared__ char  sbuf[32768];                     // 32 KB partials / flist
    __shared__ unsigned int tauv[64];
    __shared__ int          qcnt[64];

    unsigned int* partials = (unsigned int*)sbuf;     // [128 slots][64 q]
    uint2*        flist    = (uint2*)sbuf;            // [64 q][FCAP] (d_bits, idx)

    int tid = threadIdx.x;
    int b   = blockIdx.y;
    const float4* pb = pts4 + (size_t)b * NPTS;

    // ---- stage SoA packed-f16 coords (RN conversion) ----
    for (int j = tid; j < NPTS / 2; j += 1024) {
        float4 p0 = pb[2 * j], p1 = pb[2 * j + 1];
        h2 hx = { (_Float16)p0.x, (_Float16)p1.x };
        h2 hy = { (_Float16)p0.y, (_Float16)p1.y };
        h2 hz = { (_Float16)p0.z, (_Float16)p1.z };
        Phx[j] = __builtin_bit_cast(unsigned int, hx);
        Phy[j] = __builtin_bit_cast(unsigned int, hy);
        Phz[j] = __builtin_bit_cast(unsigned int, hz);
    }

    int wave = tid >> 6, lane = tid & 63;
    int q  = (wave >> 3) * 32 + (lane & 31);   // 0..63
    int ch = wave & 7;                         // chunk
    int h  = lane >> 5;                        // half-chunk
    int nq = blockIdx.x * 64 + q;

    float4 qf = pb[nq];
    h2 qx2 = { (_Float16)qf.x, (_Float16)qf.x };
    h2 qy2 = { (_Float16)qf.y, (_Float16)qf.y };
    h2 qz2 = { (_Float16)qf.z, (_Float16)qf.z };
    __syncthreads();

    const uint4* X4 = (const uint4*)Phx;
    const uint4* Y4 = (const uint4*)Phy;
    const uint4* Z4 = (const uint4*)Phz;
    int jb4 = ch * 64 + h * 32;                // uint4 base (8 cands per uint4)

    // ---- phase 1: 2 groups of 128 cands, packed branchless top-4 each ----
    {
        int slotbase = (ch * 2 + h) * 8;
        h2 binf = __builtin_bit_cast(h2, 0x7C007C00u);
#pragma unroll
        for (int sc = 0; sc < 2; ++sc) {
            h2 c0 = binf, c1 = binf, c2 = binf, c3 = binf;
            auto chain = [&](unsigned ux, unsigned uy, unsigned uz) {
                h2 dx = __builtin_bit_cast(h2, ux) - qx2;
                h2 dy = __builtin_bit_cast(h2, uy) - qy2;
                h2 dz = __builtin_bit_cast(h2, uz) - qz2;
                h2 d  = __builtin_elementwise_fma(dx, dx,
                         __builtin_elementwise_fma(dy, dy, dz * dz));
                h2 t;
                t = __builtin_elementwise_min(d, c0); d = __builtin_elementwise_max(d, c0); c0 = t;
                t = __builtin_elementwise_min(d, c1); d = __builtin_elementwise_max(d, c1); c1 = t;
                t = __builtin_elementwise_min(d, c2); d = __builtin_elementwise_max(d, c2); c2 = t;
                t = __builtin_elementwise_min(d, c3); d = __builtin_elementwise_max(d, c3); c3 = t;
            };
#pragma unroll 4
            for (int j4 = 0; j4 < 16; ++j4) {
                uint4 xu = X4[jb4 + sc * 16 + j4];
                uint4 yu = Y4[jb4 + sc * 16 + j4];
                uint4 zu = Z4[jb4 + sc * 16 + j4];
                chain(xu.x, yu.x, zu.x);
                chain(xu.y, yu.y, zu.y);
                chain(xu.z, yu.z, zu.z);
                chain(xu.w, yu.w, zu.w);
            }
            // transposed: [slot][q] -> writes hit bank q%32 (2-way, free)
            partials[(slotbase + sc * 4 + 0) * 64 + q] = __builtin_bit_cast(unsigned int, c0);
            partials[(slotbase + sc * 4 + 1) * 64 + q] = __builtin_bit_cast(unsigned int, c1);
            partials[(slotbase + sc * 4 + 2) * 64 + q] = __builtin_bit_cast(unsigned int, c2);
            partials[(slotbase + sc * 4 + 3) * 64 + q] = __builtin_bit_cast(unsigned int, c3);
        }
    }
    __syncthreads();

    // ---- merge (one wave): tau_hat = 16th smallest of 256 f16 partials ----
    if (tid < 64) {
        unsigned int mb[16];
#pragma unroll
        for (int j = 0; j < 16; ++j) mb[j] = 0x7FFFFFFFu;
        for (int slot = 0; slot < 128; ++slot) {
            unsigned int u = partials[slot * 64 + tid];   // lane-consecutive
            unsigned int v = u & 0xFFFFu;
#pragma unroll
            for (int hf = 0; hf < 2; ++hf) {
                if (v < mb[15]) {
                    unsigned int x = v;
#pragma unroll
                    for (int j = 0; j < 16; ++j) {
                        unsigned int lo = x < mb[j] ? x : mb[j];
                        x = x > mb[j] ? x : mb[j];
                        mb[j] = lo;
                    }
                }
                v = u >> 16;
            }
        }
        // inflate: covers |d_h - d_f32| (coord RN err + f16 arith) both ways
        float tau = (float)__builtin_bit_cast(_Float16, (unsigned short)mb[15]);
        float tcf = tau + 0.04f * sqrtf(tau) + 2.5e-4f;
        unsigned int tcb = (unsigned int)__builtin_bit_cast(unsigned short, (_Float16)tcf) + 1u;
        tauv[tid] = tcb;
        qcnt[tid] = 0;
    }
    __syncthreads();   // partials dead; sbuf reused as flist

    // ---- phase 2: collect superset, materialize EXACT f32 distances ----
    {
        unsigned int tcb = tauv[q];
        uint2* myq = flist + q * FCAP;
        auto push = [&](int gidx) {
            float xd = dist2(qf, pb[gidx]);          // exact f32 (parallel gather)
            int pos = atomicAdd(&qcnt[q], 1);
            if (pos < FCAP) myq[pos] = make_uint2(__builtin_bit_cast(unsigned int, xd),
                                                  (unsigned int)gidx);
        };
        auto coll = [&](unsigned ux, unsigned uy, unsigned uz, int ce) {
            h2 dx = __builtin_bit_cast(h2, ux) - qx2;
            h2 dy = __builtin_bit_cast(h2, uy) - qy2;
            h2 dz = __builtin_bit_cast(h2, uz) - qz2;
            h2 d  = __builtin_elementwise_fma(dx, dx,
                     __builtin_elementwise_fma(dy, dy, dz * dz));
            unsigned int du = __builtin_bit_cast(unsigned int, d);
            if ((du & 0xFFFFu) <= tcb) push(ce);
            if ((du >> 16)     <= tcb) push(ce + 1);
        };
#pragma unroll 2
        for (int j4 = 0; j4 < 32; ++j4) {
            uint4 xu = X4[jb4 + j4];
            uint4 yu = Y4[jb4 + j4];
            uint4 zu = Z4[jb4 + j4];
            int cb = ((jb4 + j4) * 4) * 2;
            coll(xu.x, yu.x, zu.x, cb);
            coll(xu.y, yu.y, zu.y, cb + 2);
            coll(xu.z, yu.z, zu.z, cb + 4);
            coll(xu.w, yu.w, zu.w, cb + 6);
        }
    }
    __syncthreads();

    // ---- final: LDS-only lexicographic (d asc, idx asc) top-16 ----
    // == jax.lax.top_k(-d2) stable tie-break; independent of append order.
    if (tid < 64) {
        int nc = qcnt[tid];
        nc = nc > FCAP ? FCAP : nc;
        const uint2* L = flist + tid * FCAP;
        float bd[16]; int bi[16];
#pragma unroll
        for (int j = 0; j < 16; ++j) { bd[j] = __builtin_inff(); bi[j] = 0; }
        for (int j = 0; j < nc; ++j) {
            uint2 e = L[j];
            float x  = __builtin_bit_cast(float, e.x);
            int   xi = (int)e.y;
#pragma unroll
            for (int t = 0; t < 16; ++t) {
                bool c = (x < bd[t]) || (x == bd[t] && xi < bi[t]);
                float nd = c ? x  : bd[t];
                int   ni = c ? xi : bi[t];
                float od = c ? bd[t] : x;
                int   oi = c ? bi[t] : xi;
                bd[t] = nd; bi[t] = ni; x = od; xi = oi;
            }
        }
        int* op = idxout + ((size_t)b * NPTS + blockIdx.x * 64 + tid) * KNN;
#pragma unroll
        for (int j = 0; j < 16; ++j) op[j] = bi[j];
    }
}

// ---------------------------------------------------------------------------
// Kernel B: fully-register MFMA MLP (unchanged from rounds 4-7).
// ---------------------------------------------------------------------------
__global__ __launch_bounds__(256, 2) void mlp_kernel(
    const float4* __restrict__ pts4, const int* __restrict__ idxin,
    const float* __restrict__ W0, const float* __restrict__ b0,
    const float* __restrict__ W1, const float* __restrict__ b1,
    const float* __restrict__ W2, const float* __restrict__ b2,
    float* __restrict__ out) {

    int tid  = threadIdx.x;
    int wave = tid >> 6, lane = tid & 63;
    int g = lane >> 4, i = lane & 15;

    h2 w0x[8], w0y[8], w0z[8], w0b[8];
#pragma unroll
    for (int s = 0; s < 2; ++s)
#pragma unroll
        for (int v = 0; v < 4; ++v) {
            int c0 = 32 * s + 8 * g + 2 * v;
            w0x[s * 4 + v] = pk2(W0[c0 * 3 + 0], W0[c0 * 3 + 3]);
            w0y[s * 4 + v] = pk2(W0[c0 * 3 + 1], W0[c0 * 3 + 4]);
            w0z[s * 4 + v] = pk2(W0[c0 * 3 + 2], W0[c0 * 3 + 5]);
            w0b[s * 4 + v] = pk2(b0[c0], b0[c0 + 1]);
        }
    h2 b1p[8];
#pragma unroll
    for (int s = 0; s < 2; ++s)
#pragma unroll
        for (int v = 0; v < 4; ++v) {
            int c0 = 32 * s + 16 * (v >> 1) + 4 * g + 2 * (v & 1);
            b1p[s * 4 + v] = pk2(b1[c0], b1[c0 + 1]);
        }
    h8 wf1[4][2];
#pragma unroll
    for (int t = 0; t < 4; ++t)
#pragma unroll
        for (int s = 0; s < 2; ++s) {
            const float* p = W1 + (16 * t + i) * 64 + 32 * s + 8 * g;
            h8 f;
#pragma unroll
            for (int j = 0; j < 8; ++j) f[j] = (_Float16)p[j];
            wf1[t][s] = f;
        }
    h8 wf2[8][2];
#pragma unroll
    for (int t = 0; t < 8; ++t)
#pragma unroll
        for (int s = 0; s < 2; ++s) {
            const float* p = W2 + (16 * t + i) * 64;
            h8 f;
#pragma unroll
            for (int j = 0; j < 8; ++j) {
                int vc = 32 * s + 16 * (j >> 2) + 4 * g + (j & 3);
                f[j] = (_Float16)p[vc];
            }
            wf2[t][s] = f;
        }

    int gw = blockIdx.x * 4 + wave;
    int b  = gw >> 8;
    int n0 = (gw & 255) * 16;

    const float4* pb = pts4 + (size_t)b * NPTS;
    float4 q = pb[n0 + i];
    const int* ip = idxin + ((size_t)b * NPTS + n0 + i) * KNN;

    float mx[8][4];
#pragma unroll
    for (int t = 0; t < 8; ++t)
#pragma unroll
        for (int r = 0; r < 4; ++r) mx[t][r] = -3.4e38f;

    for (int it = 0; it < KNN; ++it) {
        int mi = ip[it];
        float4 p = pb[mi];
        float rx = p.x - q.x, ry = p.y - q.y, rz = p.z - q.z;
        h2 rxx = pk2(rx, rx), ryy = pk2(ry, ry), rzz = pk2(rz, rz);

        h8 h0f[2];
#pragma unroll
        for (int s = 0; s < 2; ++s)
#pragma unroll
            for (int v = 0; v < 4; ++v) {
                h2 hh = __builtin_elementwise_fma(w0z[s * 4 + v], rzz,
                         __builtin_elementwise_fma(w0y[s * 4 + v], ryy,
                          __builtin_elementwise_fma(w0x[s * 4 + v], rxx, w0b[s * 4 + v])));
                hh = __builtin_elementwise_max(hh, (h2)(_Float16)0.0f);
                h0f[s][2 * v]     = hh.x;
                h0f[s][2 * v + 1] = hh.y;
            }

        f4 d1[4];
#pragma unroll
        for (int t = 0; t < 4; ++t) {
            d1[t] = (f4)0.0f;
#pragma unroll
            for (int s = 0; s < 2; ++s)
                d1[t] = __builtin_amdgcn_mfma_f32_16x16x32_f16(wf1[t][s], h0f[s], d1[t], 0, 0, 0);
        }

        h8 h1f[2];
#pragma unroll
        for (int s = 0; s < 2; ++s)
#pragma unroll
            for (int v = 0; v < 4; ++v) {
                int t = 2 * s + (v >> 1), r0 = 2 * (v & 1);
                h2 w = pk2(d1[t][r0], d1[t][r0 + 1]);
                w = w + b1p[s * 4 + v];
                w = __builtin_elementwise_max(w, (h2)(_Float16)0.0f);
                h1f[s][2 * v]     = w.x;
                h1f[s][2 * v + 1] = w.y;
            }

#pragma unroll
        for (int t = 0; t < 8; ++t) {
            f4 d2 = (f4)0.0f;
#pragma unroll
            for (int s = 0; s < 2; ++s)
                d2 = __builtin_amdgcn_mfma_f32_16x16x32_f16(wf2[t][s], h1f[s], d2, 0, 0, 0);
#pragma unroll
            for (int r = 0; r < 4; ++r) mx[t][r] = fmaxf(mx[t][r], d2[r]);
        }
    }

    size_t ob = (size_t)b * 128 * NPTS + n0 + i;
#pragma unroll
    for (int t = 0; t < 8; ++t)
#pragma unroll
        for (int r = 0; r < 4; ++r) {
            int chn = 16 * t + 4 * g + r;
            float v = fmaxf(mx[t][r] + b2[chn], 0.0f);
            out[ob + (size_t)chn * NPTS] = v;
        }
}

// ---------------------------------------------------------------------------
extern "C" void kernel_launch(void* const* d_in, const int* in_sizes, int n_in,
                              void* d_out, int out_size, void* d_ws, size_t ws_size,
                              hipStream_t stream) {
    (void)in_sizes; (void)n_in; (void)out_size; (void)ws_size;
    const float* xyz = (const float*)d_in[0];
    const float* W0  = (const float*)d_in[1];
    const float* b0  = (const float*)d_in[2];
    const float* W1  = (const float*)d_in[3];
    const float* b1  = (const float*)d_in[4];
    const float* W2  = (const float*)d_in[5];
    const float* b2  = (const float*)d_in[6];
    float* out = (float*)d_out;

    char* ws = (char*)d_ws;
    float4* pts4 = (float4*)ws;                                     // 512 KB
    int*    idxb = (int*)(ws + (size_t)NB * NPTS * sizeof(float4)); // 2 MB

    prep_kernel<<<dim3(NB * NPTS / 256), dim3(256), 0, stream>>>(xyz, pts4);
    knn_kernel<<<dim3(NPTS / 64, NB), dim3(1024), 0, stream>>>(pts4, idxb);
    mlp_kernel<<<dim3(512), dim3(256), 0, stream>>>(
        pts4, idxb, W0, b0, W1, b1, W2, b2, out);
}

// Round 9
// 143.730 us; speedup vs baseline: 1.3540x; 1.1276x over previous
//
#include <hip/hip_runtime.h>
#include <cstddef>

#define NB   8
#define NPTS 4096
#define KNN  16
#define FCAP 64    // per-query collected-candidate capacity (pow2)

typedef _Float16 h2 __attribute__((ext_vector_type(2)));
typedef _Float16 h8 __attribute__((ext_vector_type(8)));
typedef float    f4 __attribute__((ext_vector_type(4)));

static __device__ __forceinline__ h2 pk2(float a, float b) {
    return __builtin_bit_cast(h2, __builtin_amdgcn_cvt_pkrtz(a, b));
}

// Exact f32 distance (sq-form). Same fmaf nesting as prep's sq -> self-dist
// is exactly 0. Used ONLY for the exact candidate distances.
static __device__ __forceinline__ float dist2(float4 Q, float4 p) {
    float dot = fmaf(Q.z, p.z, fmaf(Q.y, p.y, Q.x * p.x));
    return fmaf(-2.0f, dot, Q.w + p.w);
}

// ---------------------------------------------------------------------------
// Kernel P: pack pts4[b][n] = (x, y, z, x*x+y*y+z*z) from xyz[B][3][N]
// ---------------------------------------------------------------------------
__global__ __launch_bounds__(256) void prep_kernel(const float* __restrict__ xyz,
                                                   float4* __restrict__ pts4) {
    int i = blockIdx.x * 256 + threadIdx.x;
    int b = i >> 12;
    int n = i & (NPTS - 1);
    const float* base = xyz + (size_t)b * 3 * NPTS;
    float x = base[n];
    float y = base[NPTS + n];
    float z = base[2 * NPTS + n];
    float sq = fmaf(z, z, fmaf(y, y, x * x));   // same nesting as dist2's dot
    pts4[i] = make_float4(x, y, z, sq);
}

// ---------------------------------------------------------------------------
// Kernel A: exact 16-NN via packed-f16 pruning + exact f32 final select.
//  vs round 8 (stall-focused):
//   - phase 1 & 2: two independent A/B chain streams interleaved (ILP 2x)
//   - phase 2 collects indices ONLY (no global loads in hot loop); a flat
//     1024-thread sweep then fills exact f32 distances with batched gathers
//   - merge parallelized 2-level: 4 lanes/query over 32 slots -> sorted-16
//     lists -> per-query level-2 with sorted-early-break
// ---------------------------------------------------------------------------
__global__ __launch_bounds__(1024, 8) void knn_kernel(const float4* __restrict__ pts4,
                                                      int* __restrict__ idxout) {
    __shared__ unsigned int Phx[NPTS / 2];            // 8 KB  x-pairs (h2)
    __shared__ unsigned int Phy[NPTS / 2];            // 8 KB
    __shared__ unsigned int Phz[NPTS / 2];            // 8 KB
    __shared__ char  sbuf[40960];                     // 40 KB phase-shared
    __shared__ unsigned int tauv[64];
    __shared__ int          qcnt[64];

    unsigned int*   partials = (unsigned int*)sbuf;            // [128 slots][64 q] 32KB
    unsigned short* mbuf     = (unsigned short*)(sbuf + 32768);// [4*16][64 q]      8KB
    unsigned int*   fidx     = (unsigned int*)sbuf;            // [64 q][FCAP]     16KB
    unsigned int*   fdist    = (unsigned int*)(sbuf + 16384);  // [64 q][FCAP]     16KB

    int tid = threadIdx.x;
    int b   = blockIdx.y;
    const float4* pb = pts4 + (size_t)b * NPTS;

    // ---- stage SoA packed-f16 coords (RN conversion) ----
    for (int j = tid; j < NPTS / 2; j += 1024) {
        float4 p0 = pb[2 * j], p1 = pb[2 * j + 1];
        h2 hx = { (_Float16)p0.x, (_Float16)p1.x };
        h2 hy = { (_Float16)p0.y, (_Float16)p1.y };
        h2 hz = { (_Float16)p0.z, (_Float16)p1.z };
        Phx[j] = __builtin_bit_cast(unsigned int, hx);
        Phy[j] = __builtin_bit_cast(unsigned int, hy);
        Phz[j] = __builtin_bit_cast(unsigned int, hz);
    }

    int wave = tid >> 6, lane = tid & 63;
    int q  = (wave >> 3) * 32 + (lane & 31);   // 0..63
    int ch = wave & 7;                         // chunk
    int h  = lane >> 5;                        // half-chunk
    int nq = blockIdx.x * 64 + q;

    float4 qf = pb[nq];
    h2 qx2 = { (_Float16)qf.x, (_Float16)qf.x };
    h2 qy2 = { (_Float16)qf.y, (_Float16)qf.y };
    h2 qz2 = { (_Float16)qf.z, (_Float16)qf.z };
    __syncthreads();

    const uint4* X4 = (const uint4*)Phx;
    const uint4* Y4 = (const uint4*)Phy;
    const uint4* Z4 = (const uint4*)Phz;
    int jb4 = ch * 64 + h * 32;                // uint4 base (8 cands per uint4)

    auto dcalc = [&](unsigned ux, unsigned uy, unsigned uz) -> h2 {
        h2 dx = __builtin_bit_cast(h2, ux) - qx2;
        h2 dy = __builtin_bit_cast(h2, uy) - qy2;
        h2 dz = __builtin_bit_cast(h2, uz) - qz2;
        return __builtin_elementwise_fma(dx, dx,
                __builtin_elementwise_fma(dy, dy, dz * dz));
    };

    // ---- phase 1: two interleaved streams (A: cands 0-127, B: 128-255) ----
    {
        h2 binf = __builtin_bit_cast(h2, 0x7C007C00u);
        h2 a0 = binf, a1 = binf, a2 = binf, a3 = binf;
        h2 c0 = binf, c1 = binf, c2 = binf, c3 = binf;
        auto insA = [&](h2 d) {
            h2 t;
            t = __builtin_elementwise_min(d, a0); d = __builtin_elementwise_max(d, a0); a0 = t;
            t = __builtin_elementwise_min(d, a1); d = __builtin_elementwise_max(d, a1); a1 = t;
            t = __builtin_elementwise_min(d, a2); d = __builtin_elementwise_max(d, a2); a2 = t;
            t = __builtin_elementwise_min(d, a3); d = __builtin_elementwise_max(d, a3); a3 = t;
        };
        auto insB = [&](h2 d) {
            h2 t;
            t = __builtin_elementwise_min(d, c0); d = __builtin_elementwise_max(d, c0); c0 = t;
            t = __builtin_elementwise_min(d, c1); d = __builtin_elementwise_max(d, c1); c1 = t;
            t = __builtin_elementwise_min(d, c2); d = __builtin_elementwise_max(d, c2); c2 = t;
            t = __builtin_elementwise_min(d, c3); d = __builtin_elementwise_max(d, c3); c3 = t;
        };
#pragma unroll 4
        for (int j4 = 0; j4 < 16; ++j4) {
            uint4 xA = X4[jb4 + j4],      yA = Y4[jb4 + j4],      zA = Z4[jb4 + j4];
            uint4 xB = X4[jb4 + 16 + j4], yB = Y4[jb4 + 16 + j4], zB = Z4[jb4 + 16 + j4];
            insA(dcalc(xA.x, yA.x, zA.x));
            insB(dcalc(xB.x, yB.x, zB.x));
            insA(dcalc(xA.y, yA.y, zA.y));
            insB(dcalc(xB.y, yB.y, zB.y));
            insA(dcalc(xA.z, yA.z, zA.z));
            insB(dcalc(xB.z, yB.z, zB.z));
            insA(dcalc(xA.w, yA.w, zA.w));
            insB(dcalc(xB.w, yB.w, zB.w));
        }
        int sb = (ch * 2 + h) * 8;
        partials[(sb + 0) * 64 + q] = __builtin_bit_cast(unsigned int, a0);
        partials[(sb + 1) * 64 + q] = __builtin_bit_cast(unsigned int, a1);
        partials[(sb + 2) * 64 + q] = __builtin_bit_cast(unsigned int, a2);
        partials[(sb + 3) * 64 + q] = __builtin_bit_cast(unsigned int, a3);
        partials[(sb + 4) * 64 + q] = __builtin_bit_cast(unsigned int, c0);
        partials[(sb + 5) * 64 + q] = __builtin_bit_cast(unsigned int, c1);
        partials[(sb + 6) * 64 + q] = __builtin_bit_cast(unsigned int, c2);
        partials[(sb + 7) * 64 + q] = __builtin_bit_cast(unsigned int, c3);
    }
    __syncthreads();

    // ---- merge level 1: 4 lanes/query, 32 slots (64 values) -> sorted-16 ----
    if (tid < 256) {
        int qq = tid & 63, k = tid >> 6;
        unsigned mb[16];
#pragma unroll
        for (int j = 0; j < 16; ++j) mb[j] = 0xFFFFu;
        for (int s = 0; s < 32; ++s) {
            unsigned u = partials[(k * 32 + s) * 64 + qq];   // lane-consecutive
            unsigned v = u & 0xFFFFu;
#pragma unroll
            for (int hf = 0; hf < 2; ++hf) {
                if (v < mb[15]) {
                    unsigned x = v;
#pragma unroll
                    for (int j = 0; j < 16; ++j) {
                        unsigned lo = x < mb[j] ? x : mb[j];
                        x = x > mb[j] ? x : mb[j];
                        mb[j] = lo;
                    }
                }
                v = u >> 16;
            }
        }
#pragma unroll
        for (int j = 0; j < 16; ++j) mbuf[(k * 16 + j) * 64 + qq] = (unsigned short)mb[j];
    }
    __syncthreads();

    // ---- merge level 2: 16th smallest of 4 sorted-16 lists (early break) ----
    if (tid < 64) {
        unsigned mb[16];
#pragma unroll
        for (int j = 0; j < 16; ++j) mb[j] = 0xFFFFu;
        for (int k = 0; k < 4; ++k) {
            for (int j = 0; j < 16; ++j) {
                unsigned v = (unsigned)mbuf[(k * 16 + j) * 64 + tid];
                if (v >= mb[15]) break;          // list ascending -> rest useless
                unsigned x = v;
#pragma unroll
                for (int t = 0; t < 16; ++t) {
                    unsigned lo = x < mb[t] ? x : mb[t];
                    x = x > mb[t] ? x : mb[t];
                    mb[t] = lo;
                }
            }
        }
        // inflate: covers |d_h - d_f32| (coord RN err + f16 arith) both ways
        float tau = (float)__builtin_bit_cast(_Float16, (unsigned short)mb[15]);
        float tcf = tau + 0.04f * sqrtf(tau) + 2.5e-4f;
        unsigned tcb = (unsigned)__builtin_bit_cast(unsigned short, (_Float16)tcf) + 1u;
        tauv[tid] = tcb;
        qcnt[tid] = 0;
    }
    __syncthreads();   // partials/mbuf dead; sbuf reused as fidx/fdist

    // ---- phase 2: collect indices only (pure LDS), A/B interleaved ----
    {
        unsigned tcb = tauv[q];
        auto push = [&](int gidx) {
            int pos = atomicAdd(&qcnt[q], 1);
            if (pos < FCAP) fidx[(q << 6) + pos] = (unsigned)gidx;
        };
        auto cmp2 = [&](unsigned ux, unsigned uy, unsigned uz, int cb) {
            h2 d = dcalc(ux, uy, uz);
            unsigned du = __builtin_bit_cast(unsigned, d);
            if ((du & 0xFFFFu) <= tcb) push(cb);
            if ((du >> 16)     <= tcb) push(cb + 1);
        };
#pragma unroll 2
        for (int j4 = 0; j4 < 16; ++j4) {
            uint4 xA = X4[jb4 + j4],      yA = Y4[jb4 + j4],      zA = Z4[jb4 + j4];
            uint4 xB = X4[jb4 + 16 + j4], yB = Y4[jb4 + 16 + j4], zB = Z4[jb4 + 16 + j4];
            int cbA = (jb4 + j4) * 8, cbB = (jb4 + 16 + j4) * 8;
            cmp2(xA.x, yA.x, zA.x, cbA);
            cmp2(xB.x, yB.x, zB.x, cbB);
            cmp2(xA.y, yA.y, zA.y, cbA + 2);
            cmp2(xB.y, yB.y, zB.y, cbB + 2);
            cmp2(xA.z, yA.z, zA.z, cbA + 4);
            cmp2(xB.z, yB.z, zB.z, cbB + 4);
            cmp2(xA.w, yA.w, zA.w, cbA + 6);
            cmp2(xB.w, yB.w, zB.w, cbB + 6);
        }
    }
    __syncthreads();

    // ---- sweep: exact f32 distances for collected entries (batched gathers) ----
    for (int e = tid; e < 64 * FCAP; e += 1024) {
        int qq = e >> 6, j = e & (FCAP - 1);
        int nc = qcnt[qq]; nc = nc > FCAP ? FCAP : nc;
        if (j < nc) {
            int idx = (int)fidx[e];
            float4 Qf = pb[blockIdx.x * 64 + qq];   // 64 hot lines, L1/L2 hit
            float xd = dist2(Qf, pb[idx]);
            fdist[e] = __builtin_bit_cast(unsigned, xd);
        }
    }
    __syncthreads();

    // ---- final: LDS-only lexicographic (d asc, idx asc) top-16 ----
    if (tid < 64) {
        int nc = qcnt[tid]; nc = nc > FCAP ? FCAP : nc;
        float bd[16]; int bi[16];
#pragma unroll
        for (int j = 0; j < 16; ++j) { bd[j] = __builtin_inff(); bi[j] = 0; }
        for (int j = 0; j < nc; ++j) {
            float x  = __builtin_bit_cast(float, fdist[(tid << 6) + j]);
            int   xi = (int)fidx[(tid << 6) + j];
            if (x < bd[15] || (x == bd[15] && xi < bi[15])) {
#pragma unroll
                for (int t = 0; t < 16; ++t) {
                    bool c = (x < bd[t]) || (x == bd[t] && xi < bi[t]);
                    float nd = c ? x  : bd[t];
                    int   ni = c ? xi : bi[t];
                    float od = c ? bd[t] : x;
                    int   oi = c ? bi[t] : xi;
                    bd[t] = nd; bi[t] = ni; x = od; xi = oi;
                }
            }
        }
        int* op = idxout + ((size_t)b * NPTS + blockIdx.x * 64 + tid) * KNN;
#pragma unroll
        for (int j = 0; j < 16; ++j) op[j] = bi[j];
    }
}

// ---------------------------------------------------------------------------
// Kernel B: fully-register MFMA MLP (unchanged from rounds 4-8).
// ---------------------------------------------------------------------------
__global__ __launch_bounds__(256, 2) void mlp_kernel(
    const float4* __restrict__ pts4, const int* __restrict__ idxin,
    const float* __restrict__ W0, const float* __restrict__ b0,
    const float* __restrict__ W1, const float* __restrict__ b1,
    const float* __restrict__ W2, const float* __restrict__ b2,
    float* __restrict__ out) {

    int tid  = threadIdx.x;
    int wave = tid >> 6, lane = tid & 63;
    int g = lane >> 4, i = lane & 15;

    h2 w0x[8], w0y[8], w0z[8], w0b[8];
#pragma unroll
    for (int s = 0; s < 2; ++s)
#pragma unroll
        for (int v = 0; v < 4; ++v) {
            int c0 = 32 * s + 8 * g + 2 * v;
            w0x[s * 4 + v] = pk2(W0[c0 * 3 + 0], W0[c0 * 3 + 3]);
            w0y[s * 4 + v] = pk2(W0[c0 * 3 + 1], W0[c0 * 3 + 4]);
            w0z[s * 4 + v] = pk2(W0[c0 * 3 + 2], W0[c0 * 3 + 5]);
            w0b[s * 4 + v] = pk2(b0[c0], b0[c0 + 1]);
        }
    h2 b1p[8];
#pragma unroll
    for (int s = 0; s < 2; ++s)
#pragma unroll
        for (int v = 0; v < 4; ++v) {
            int c0 = 32 * s + 16 * (v >> 1) + 4 * g + 2 * (v & 1);
            b1p[s * 4 + v] = pk2(b1[c0], b1[c0 + 1]);
        }
    h8 wf1[4][2];
#pragma unroll
    for (int t = 0; t < 4; ++t)
#pragma unroll
        for (int s = 0; s < 2; ++s) {
            const float* p = W1 + (16 * t + i) * 64 + 32 * s + 8 * g;
            h8 f;
#pragma unroll
            for (int j = 0; j < 8; ++j) f[j] = (_Float16)p[j];
            wf1[t][s] = f;
        }
    h8 wf2[8][2];
#pragma unroll
    for (int t = 0; t < 8; ++t)
#pragma unroll
        for (int s = 0; s < 2; ++s) {
            const float* p = W2 + (16 * t + i) * 64;
            h8 f;
#pragma unroll
            for (int j = 0; j < 8; ++j) {
                int vc = 32 * s + 16 * (j >> 2) + 4 * g + (j & 3);
                f[j] = (_Float16)p[vc];
            }
            wf2[t][s] = f;
        }

    int gw = blockIdx.x * 4 + wave;
    int b  = gw >> 8;
    int n0 = (gw & 255) * 16;

    const float4* pb = pts4 + (size_t)b * NPTS;
    float4 q = pb[n0 + i];
    const int* ip = idxin + ((size_t)b * NPTS + n0 + i) * KNN;

    float mx[8][4];
#pragma unroll
    for (int t = 0; t < 8; ++t)
#pragma unroll
        for (int r = 0; r < 4; ++r) mx[t][r] = -3.4e38f;

    for (int it = 0; it < KNN; ++it) {
        int mi = ip[it];
        float4 p = pb[mi];
        float rx = p.x - q.x, ry = p.y - q.y, rz = p.z - q.z;
        h2 rxx = pk2(rx, rx), ryy = pk2(ry, ry), rzz = pk2(rz, rz);

        h8 h0f[2];
#pragma unroll
        for (int s = 0; s < 2; ++s)
#pragma unroll
            for (int v = 0; v < 4; ++v) {
                h2 hh = __builtin_elementwise_fma(w0z[s * 4 + v], rzz,
                         __builtin_elementwise_fma(w0y[s * 4 + v], ryy,
                          __builtin_elementwise_fma(w0x[s * 4 + v], rxx, w0b[s * 4 + v])));
                hh = __builtin_elementwise_max(hh, (h2)(_Float16)0.0f);
                h0f[s][2 * v]     = hh.x;
                h0f[s][2 * v + 1] = hh.y;
            }

        f4 d1[4];
#pragma unroll
        for (int t = 0; t < 4; ++t) {
            d1[t] = (f4)0.0f;
#pragma unroll
            for (int s = 0; s < 2; ++s)
                d1[t] = __builtin_amdgcn_mfma_f32_16x16x32_f16(wf1[t][s], h0f[s], d1[t], 0, 0, 0);
        }

        h8 h1f[2];
#pragma unroll
        for (int s = 0; s < 2; ++s)
#pragma unroll
            for (int v = 0; v < 4; ++v) {
                int t = 2 * s + (v >> 1), r0 = 2 * (v & 1);
                h2 w = pk2(d1[t][r0], d1[t][r0 + 1]);
                w = w + b1p[s * 4 + v];
                w = __builtin_elementwise_max(w, (h2)(_Float16)0.0f);
                h1f[s][2 * v]     = w.x;
                h1f[s][2 * v + 1] = w.y;
            }

#pragma unroll
        for (int t = 0; t < 8; ++t) {
            f4 d2 = (f4)0.0f;
#pragma unroll
            for (int s = 0; s < 2; ++s)
                d2 = __builtin_amdgcn_mfma_f32_16x16x32_f16(wf2[t][s], h1f[s], d2, 0, 0, 0);
#pragma unroll
            for (int r = 0; r < 4; ++r) mx[t][r] = fmaxf(mx[t][r], d2[r]);
        }
    }

    size_t ob = (size_t)b * 128 * NPTS + n0 + i;
#pragma unroll
    for (int t = 0; t < 8; ++t)
#pragma unroll
        for (int r = 0; r < 4; ++r) {
            int chn = 16 * t + 4 * g + r;
            float v = fmaxf(mx[t][r] + b2[chn], 0.0f);
            out[ob + (size_t)chn * NPTS] = v;
        }
}

// ---------------------------------------------------------------------------
extern "C" void kernel_launch(void* const* d_in, const int* in_sizes, int n_in,
                              void* d_out, int out_size, void* d_ws, size_t ws_size,
                              hipStream_t stream) {
    (void)in_sizes; (void)n_in; (void)out_size; (void)ws_size;
    const float* xyz = (const float*)d_in[0];
    const float* W0  = (const float*)d_in[1];
    const float* b0  = (const float*)d_in[2];
    const float* W1  = (const float*)d_in[3];
    const float* b1  = (const float*)d_in[4];
    const float* W2  = (const float*)d_in[5];
    const float* b2  = (const float*)d_in[6];
    float* out = (float*)d_out;

    char* ws = (char*)d_ws;
    float4* pts4 = (float4*)ws;                                     // 512 KB
    int*    idxb = (int*)(ws + (size_t)NB * NPTS * sizeof(float4)); // 2 MB

    prep_kernel<<<dim3(NB * NPTS / 256), dim3(256), 0, stream>>>(xyz, pts4);
    knn_kernel<<<dim3(NPTS / 64, NB), dim3(1024), 0, stream>>>(pts4, idxb);
    mlp_kernel<<<dim3(512), dim3(256), 0, stream>>>(
        pts4, idxb, W0, b0, W1, b1, W2, b2, out);
}

// Round 10
// 139.773 us; speedup vs baseline: 1.3923x; 1.0283x over previous
//
#include <hip/hip_runtime.h>
#include <cstddef>

#define NB   8
#define NPTS 4096
#define KNN  16
#define FCAP 64    // per-query collected-candidate capacity

typedef _Float16 h2 __attribute__((ext_vector_type(2)));
typedef _Float16 h8 __attribute__((ext_vector_type(8)));
typedef float    f4 __attribute__((ext_vector_type(4)));

static __device__ __forceinline__ h2 pk2(float a, float b) {
    return __builtin_bit_cast(h2, __builtin_amdgcn_cvt_pkrtz(a, b));
}

#if __has_builtin(__builtin_amdgcn_fmed3f)
static __device__ __forceinline__ float MED3(float a, float b, float c) {
    return __builtin_amdgcn_fmed3f(a, b, c);
}
#else
static __device__ __forceinline__ float MED3(float a, float b, float c) {
    return fmaxf(fminf(a, b), fminf(fmaxf(a, b), c));
}
#endif

// Exact f32 distance (sq-form). Same fmaf nesting as prep's sq -> self-dist
// is exactly 0. Used ONLY for the exact candidate distances.
static __device__ __forceinline__ float dist2(float4 Q, float4 p) {
    float dot = fmaf(Q.z, p.z, fmaf(Q.y, p.y, Q.x * p.x));
    return fmaf(-2.0f, dot, Q.w + p.w);
}

// ---------------------------------------------------------------------------
// Kernel P: pack pts4[b][n] = (x, y, z, x*x+y*y+z*z) from xyz[B][3][N]
// ---------------------------------------------------------------------------
__global__ __launch_bounds__(256) void prep_kernel(const float* __restrict__ xyz,
                                                   float4* __restrict__ pts4) {
    int i = blockIdx.x * 256 + threadIdx.x;
    int b = i >> 12;
    int n = i & (NPTS - 1);
    const float* base = xyz + (size_t)b * 3 * NPTS;
    float x = base[n];
    float y = base[NPTS + n];
    float z = base[2 * NPTS + n];
    float sq = fmaf(z, z, fmaf(y, y, x * x));   // same nesting as dist2's dot
    pts4[i] = make_float4(x, y, z, sq);
}

// ---------------------------------------------------------------------------
// Kernel A: exact 16-NN with MFMA-computed pruning keys.
//  Key: g(c) = |p_h|^2 - 2 q_h . p_h  (exact f32 MFMA arithmetic on f16 inputs)
//       == per-query-constant shift of d^2, so selection on g == selection on d^2.
//  A-frag (cands): lanes 0-15 hold (x,y,z,|p|^2) f16 at k=0..3; rest zero.
//  B-frag (queries): lanes 0-15 hold (-2qx,-2qy,-2qz,1) f16; rest zero.
//  D: col=lane&15 (query), row=(lane>>4)*4+r (cand)  [proven layout, mlp kernel].
//  Phase 1: per-lane sorted-4 (min + 3 med3) over 64 tiles -> 64 partials/query.
//  Merge:  2-level -> tau_hat = 16th of 64; inflate by RIGOROUS bound:
//          E = smax*2^-11 + 2*sum|q_h|*(pmax*2^-11) + 2*sum|dq|*pmax  (+1e-4 f32)
//          with pmax/smax reduced from the actual staged batch. Collect g<=tau+2E.
//  Phase 2: same MFMA (deterministic), push indices (LDS atomic).
//  Sweep:  parallel exact f32 distances; final: lexicographic (d,idx) top-16
//          == jax.lax.top_k tie-break. FCAP overflow -> exact brute-force fallback.
// ---------------------------------------------------------------------------
__global__ __launch_bounds__(1024, 8) void knn_kernel(const float4* __restrict__ pts4,
                                                      int* __restrict__ idxout) {
    __shared__ uint2 Pm[NPTS];                        // 32 KB (x,y,z,s as 4xf16)
    __shared__ char  sbuf[32768];                     // 32 KB phase-shared
    __shared__ float tauv[64];
    __shared__ int   qcnt[64];
    __shared__ unsigned pmaxu, smaxu;

    float*    partials = (float*)sbuf;                // [64 slots][64 q] 16 KB
    float*    mbuf     = (float*)(sbuf + 16384);      // [4*16][64 q]    16 KB
    unsigned* fidx     = (unsigned*)sbuf;             // [FCAP][64 q]    16 KB
    float*    fdist    = (float*)(sbuf + 16384);      // [FCAP][64 q]    16 KB

    int tid = threadIdx.x;
    int b   = blockIdx.y;
    const float4* pb = pts4 + (size_t)b * NPTS;

    if (tid == 0) { pmaxu = 0u; smaxu = 0u; }
    __syncthreads();

    // ---- stage (x,y,z,s) as f16x4; reduce exact pmax/smax of the batch ----
    {
        float lm = 0.0f, ls = 0.0f;
        for (int j = tid; j < NPTS; j += 1024) {
            float4 p = pb[j];
            lm = fmaxf(lm, fmaxf(fabsf(p.x), fmaxf(fabsf(p.y), fabsf(p.z))));
            ls = fmaxf(ls, p.w);
            h2 lo = { (_Float16)p.x, (_Float16)p.y };
            h2 hi = { (_Float16)p.z, (_Float16)p.w };
            Pm[j].x = __builtin_bit_cast(unsigned, lo);
            Pm[j].y = __builtin_bit_cast(unsigned, hi);
        }
        atomicMax(&pmaxu, __builtin_bit_cast(unsigned, lm));   // f32>=0: uint order
        atomicMax(&smaxu, __builtin_bit_cast(unsigned, ls));
    }

    int wave = tid >> 6, lane = tid & 63;
    int qg = wave >> 2;           // query group 0..3 (16 q each)
    int cq = wave & 3;            // candidate quarter 0..3 (1024 cands)
    int qcol = lane & 15;
    int rg   = lane >> 4;         // D row group 0..3
    int q  = qg * 16 + qcol;      // 0..63
    int nq = (blockIdx.x << 6) + q;
    int cbase = cq * 1024;

    float4 qf = pb[nq];
    // B-frag: lanes 0-15 hold (-2qx,-2qy,-2qz,1); others zero (k>=8 slots).
    uint4 bu = {0u, 0u, 0u, 0u};
    if (rg == 0) {
        h2 b01 = { (_Float16)(-2.0f * qf.x), (_Float16)(-2.0f * qf.y) };
        h2 b23 = { (_Float16)(-2.0f * qf.z), (_Float16)1.0f };
        bu.x = __builtin_bit_cast(unsigned, b01);
        bu.y = __builtin_bit_cast(unsigned, b23);
    }
    h8 bq = __builtin_bit_cast(h8, bu);
    __syncthreads();

    // ---- phase 1: 64 MFMA tiles, per-lane sorted-4 via min+med3 ----
    {
        float c0 = __builtin_inff(), c1 = c0, c2 = c0, c3 = c0;
#pragma unroll 2
        for (int t = 0; t < 64; ++t) {
            uint4 au = {0u, 0u, 0u, 0u};
            if (rg == 0) {
                uint2 pd = Pm[cbase + t * 16 + qcol];   // lane==qcol for rg==0
                au.x = pd.x; au.y = pd.y;
            }
            f4 d = __builtin_amdgcn_mfma_f32_16x16x32_f16(
                __builtin_bit_cast(h8, au), bq, (f4)0.0f, 0, 0, 0);
#pragma unroll
            for (int r = 0; r < 4; ++r) {
                float x = d[r];
                float p0 = c0, p1 = c1, p2 = c2;
                c0 = fminf(p0, x);
                c1 = MED3(x, p0, c1);
                c2 = MED3(x, p1, c2);
                c3 = MED3(x, p2, c3);
            }
        }
        int sb = (cq * 4 + rg) * 4;
        partials[(sb + 0) * 64 + q] = c0;
        partials[(sb + 1) * 64 + q] = c1;
        partials[(sb + 2) * 64 + q] = c2;
        partials[(sb + 3) * 64 + q] = c3;
    }
    __syncthreads();

    // ---- merge level 1: 4 mergers/query x 16 slots -> sorted-16 ----
    if (tid < 256) {
        int qq = tid & 63, k = tid >> 6;
        float mb[16];
#pragma unroll
        for (int j = 0; j < 16; ++j) mb[j] = __builtin_inff();
        for (int s = 0; s < 16; ++s) {
            float v = partials[(k * 16 + s) * 64 + qq];
            float prev = mb[0];
            mb[0] = fminf(mb[0], v);
#pragma unroll
            for (int i = 1; i < 16; ++i) {
                float cur = mb[i];
                mb[i] = MED3(v, prev, cur);
                prev = cur;
            }
        }
#pragma unroll
        for (int j = 0; j < 16; ++j) mbuf[(k * 16 + j) * 64 + qq] = mb[j];
    }
    __syncthreads();

    // ---- merge level 2: 16th of 4 sorted lists; rigorous threshold ----
    if (tid < 64) {
        float mb[16];
#pragma unroll
        for (int j = 0; j < 16; ++j) mb[j] = __builtin_inff();
        for (int k = 0; k < 4; ++k) {
            for (int j = 0; j < 16; ++j) {
                float v = mbuf[(k * 16 + j) * 64 + tid];
                if (v >= mb[15]) break;             // ascending list
                float prev = mb[0];
                mb[0] = fminf(mb[0], v);
#pragma unroll
                for (int i = 1; i < 16; ++i) {
                    float cur = mb[i];
                    mb[i] = MED3(v, prev, cur);
                    prev = cur;
                }
            }
        }
        float4 q2 = pb[(blockIdx.x << 6) + tid];
        float qhx = (float)(_Float16)q2.x;
        float qhy = (float)(_Float16)q2.y;
        float qhz = (float)(_Float16)q2.z;
        float sumq  = fabsf(qhx) + fabsf(qhy) + fabsf(qhz);
        float sumdq = fabsf(q2.x - qhx) + fabsf(q2.y - qhy) + fabsf(q2.z - qhz);
        float pmax = __builtin_bit_cast(float, pmaxu);
        float smax = __builtin_bit_cast(float, smaxu);
        const float r11 = 4.8828125e-4f;            // 2^-11
        float E = smax * r11 + 2.0f * sumq * (pmax * r11) + 2.0f * sumdq * pmax + 1e-4f;
        tauv[tid] = mb[15] + 2.0f * E;
        qcnt[tid] = 0;
    }
    __syncthreads();   // partials/mbuf dead; reuse as fidx/fdist

    // ---- phase 2: same MFMA, push candidate indices with g <= tau_c ----
    {
        float tc = tauv[q];
#pragma unroll 2
        for (int t = 0; t < 64; ++t) {
            uint4 au = {0u, 0u, 0u, 0u};
            if (rg == 0) {
                uint2 pd = Pm[cbase + t * 16 + qcol];
                au.x = pd.x; au.y = pd.y;
            }
            f4 d = __builtin_amdgcn_mfma_f32_16x16x32_f16(
                __builtin_bit_cast(h8, au), bq, (f4)0.0f, 0, 0, 0);
#pragma unroll
            for (int r = 0; r < 4; ++r) {
                if (d[r] <= tc) {
                    int pos = atomicAdd(&qcnt[q], 1);
                    if (pos < FCAP) fidx[pos * 64 + q] = (unsigned)(cbase + t * 16 + rg * 4 + r);
                }
            }
        }
    }
    __syncthreads();

    // ---- sweep: exact f32 distances, fully parallel gathers ----
    for (int e = tid; e < FCAP * 64; e += 1024) {
        int j = e >> 6, qq = e & 63;
        int nc = qcnt[qq]; nc = nc > FCAP ? FCAP : nc;
        if (j < nc) {
            float4 Qf = pb[(blockIdx.x << 6) + qq];
            fdist[e] = dist2(Qf, pb[fidx[e]]);
        }
    }
    __syncthreads();

    // ---- final: lexicographic (d asc, idx asc) top-16; overflow fallback ----
    if (tid < 64) {
        int nqf = (blockIdx.x << 6) + tid;
        float4 Qf = pb[nqf];
        float bd[16]; int bi[16];
#pragma unroll
        for (int j = 0; j < 16; ++j) { bd[j] = __builtin_inff(); bi[j] = 0; }
        int cnt = qcnt[tid];
        if (cnt <= FCAP) {
            for (int j = 0; j < cnt; ++j) {
                float x  = fdist[j * 64 + tid];
                int   xi = (int)fidx[j * 64 + tid];
                if (x < bd[15] || (x == bd[15] && xi < bi[15])) {
#pragma unroll
                    for (int t = 0; t < 16; ++t) {
                        bool c = (x < bd[t]) || (x == bd[t] && xi < bi[t]);
                        float nd = c ? x  : bd[t];
                        int   ni = c ? xi : bi[t];
                        float od = c ? bd[t] : x;
                        int   oi = c ? bi[t] : xi;
                        bd[t] = nd; bi[t] = ni; x = od; xi = oi;
                    }
                }
            }
        } else {
            // safety fallback: exact brute-force scan (expected never taken)
            for (int m = 0; m < NPTS; ++m) {
                float x = dist2(Qf, pb[m]);
                int  xi = m;
                if (x < bd[15] || (x == bd[15] && xi < bi[15])) {
#pragma unroll
                    for (int t = 0; t < 16; ++t) {
                        bool c = (x < bd[t]) || (x == bd[t] && xi < bi[t]);
                        float nd = c ? x  : bd[t];
                        int   ni = c ? xi : bi[t];
                        float od = c ? bd[t] : x;
                        int   oi = c ? bi[t] : xi;
                        bd[t] = nd; bi[t] = ni; x = od; xi = oi;
                    }
                }
            }
        }
        int* op = idxout + ((size_t)b * NPTS + nqf) * KNN;
#pragma unroll
        for (int j = 0; j < 16; ++j) op[j] = bi[j];
    }
}

// ---------------------------------------------------------------------------
// Kernel B: fully-register MFMA MLP (unchanged from rounds 4-9).
// ---------------------------------------------------------------------------
__global__ __launch_bounds__(256, 2) void mlp_kernel(
    const float4* __restrict__ pts4, const int* __restrict__ idxin,
    const float* __restrict__ W0, const float* __restrict__ b0,
    const float* __restrict__ W1, const float* __restrict__ b1,
    const float* __restrict__ W2, const float* __restrict__ b2,
    float* __restrict__ out) {

    int tid  = threadIdx.x;
    int wave = tid >> 6, lane = tid & 63;
    int g = lane >> 4, i = lane & 15;

    h2 w0x[8], w0y[8], w0z[8], w0b[8];
#pragma unroll
    for (int s = 0; s < 2; ++s)
#pragma unroll
        for (int v = 0; v < 4; ++v) {
            int c0 = 32 * s + 8 * g + 2 * v;
            w0x[s * 4 + v] = pk2(W0[c0 * 3 + 0], W0[c0 * 3 + 3]);
            w0y[s * 4 + v] = pk2(W0[c0 * 3 + 1], W0[c0 * 3 + 4]);
            w0z[s * 4 + v] = pk2(W0[c0 * 3 + 2], W0[c0 * 3 + 5]);
            w0b[s * 4 + v] = pk2(b0[c0], b0[c0 + 1]);
        }
    h2 b1p[8];
#pragma unroll
    for (int s = 0; s < 2; ++s)
#pragma unroll
        for (int v = 0; v < 4; ++v) {
            int c0 = 32 * s + 16 * (v >> 1) + 4 * g + 2 * (v & 1);
            b1p[s * 4 + v] = pk2(b1[c0], b1[c0 + 1]);
        }
    h8 wf1[4][2];
#pragma unroll
    for (int t = 0; t < 4; ++t)
#pragma unroll
        for (int s = 0; s < 2; ++s) {
            const float* p = W1 + (16 * t + i) * 64 + 32 * s + 8 * g;
            h8 f;
#pragma unroll
            for (int j = 0; j < 8; ++j) f[j] = (_Float16)p[j];
            wf1[t][s] = f;
        }
    h8 wf2[8][2];
#pragma unroll
    for (int t = 0; t < 8; ++t)
#pragma unroll
        for (int s = 0; s < 2; ++s) {
            const float* p = W2 + (16 * t + i) * 64;
            h8 f;
#pragma unroll
            for (int j = 0; j < 8; ++j) {
                int vc = 32 * s + 16 * (j >> 2) + 4 * g + (j & 3);
                f[j] = (_Float16)p[vc];
            }
            wf2[t][s] = f;
        }

    int gw = blockIdx.x * 4 + wave;
    int b  = gw >> 8;
    int n0 = (gw & 255) * 16;

    const float4* pb = pts4 + (size_t)b * NPTS;
    float4 q = pb[n0 + i];
    const int* ip = idxin + ((size_t)b * NPTS + n0 + i) * KNN;

    float mx[8][4];
#pragma unroll
    for (int t = 0; t < 8; ++t)
#pragma unroll
        for (int r = 0; r < 4; ++r) mx[t][r] = -3.4e38f;

    for (int it = 0; it < KNN; ++it) {
        int mi = ip[it];
        float4 p = pb[mi];
        float rx = p.x - q.x, ry = p.y - q.y, rz = p.z - q.z;
        h2 rxx = pk2(rx, rx), ryy = pk2(ry, ry), rzz = pk2(rz, rz);

        h8 h0f[2];
#pragma unroll
        for (int s = 0; s < 2; ++s)
#pragma unroll
            for (int v = 0; v < 4; ++v) {
                h2 hh = __builtin_elementwise_fma(w0z[s * 4 + v], rzz,
                         __builtin_elementwise_fma(w0y[s * 4 + v], ryy,
                          __builtin_elementwise_fma(w0x[s * 4 + v], rxx, w0b[s * 4 + v])));
                hh = __builtin_elementwise_max(hh, (h2)(_Float16)0.0f);
                h0f[s][2 * v]     = hh.x;
                h0f[s][2 * v + 1] = hh.y;
            }

        f4 d1[4];
#pragma unroll
        for (int t = 0; t < 4; ++t) {
            d1[t] = (f4)0.0f;
#pragma unroll
            for (int s = 0; s < 2; ++s)
                d1[t] = __builtin_amdgcn_mfma_f32_16x16x32_f16(wf1[t][s], h0f[s], d1[t], 0, 0, 0);
        }

        h8 h1f[2];
#pragma unroll
        for (int s = 0; s < 2; ++s)
#pragma unroll
            for (int v = 0; v < 4; ++v) {
                int t = 2 * s + (v >> 1), r0 = 2 * (v & 1);
                h2 w = pk2(d1[t][r0], d1[t][r0 + 1]);
                w = w + b1p[s * 4 + v];
                w = __builtin_elementwise_max(w, (h2)(_Float16)0.0f);
                h1f[s][2 * v]     = w.x;
                h1f[s][2 * v + 1] = w.y;
            }

#pragma unroll
        for (int t = 0; t < 8; ++t) {
            f4 d2 = (f4)0.0f;
#pragma unroll
            for (int s = 0; s < 2; ++s)
                d2 = __builtin_amdgcn_mfma_f32_16x16x32_f16(wf2[t][s], h1f[s], d2, 0, 0, 0);
#pragma unroll
            for (int r = 0; r < 4; ++r) mx[t][r] = fmaxf(mx[t][r], d2[r]);
        }
    }

    size_t ob = (size_t)b * 128 * NPTS + n0 + i;
#pragma unroll
    for (int t = 0; t < 8; ++t)
#pragma unroll
        for (int r = 0; r < 4; ++r) {
            int chn = 16 * t + 4 * g + r;
            float v = fmaxf(mx[t][r] + b2[chn], 0.0f);
            out[ob + (size_t)chn * NPTS] = v;
        }
}

// ---------------------------------------------------------------------------
extern "C" void kernel_launch(void* const* d_in, const int* in_sizes, int n_in,
                              void* d_out, int out_size, void* d_ws, size_t ws_size,
                              hipStream_t stream) {
    (void)in_sizes; (void)n_in; (void)out_size; (void)ws_size;
    const float* xyz = (const float*)d_in[0];
    const float* W0  = (const float*)d_in[1];
    const float* b0  = (const float*)d_in[2];
    const float* W1  = (const float*)d_in[3];
    const float* b1  = (const float*)d_in[4];
    const float* W2  = (const float*)d_in[5];
    const float* b2  = (const float*)d_in[6];
    float* out = (float*)d_out;

    char* ws = (char*)d_ws;
    float4* pts4 = (float4*)ws;                                     // 512 KB
    int*    idxb = (int*)(ws + (size_t)NB * NPTS * sizeof(float4)); // 2 MB

    prep_kernel<<<dim3(NB * NPTS / 256), dim3(256), 0, stream>>>(xyz, pts4);
    knn_kernel<<<dim3(NPTS / 64, NB), dim3(1024), 0, stream>>>(pts4, idxb);
    mlp_kernel<<<dim3(512), dim3(256), 0, stream>>>(
        pts4, idxb, W0, b0, W1, b1, W2, b2, out);
}